// Round 10
// baseline (13868.146 us; speedup 1.0000x reference)
//
#include <hip/hip_runtime.h>
#include <stdint.h>

#define HW 25600
#define C  2048
#define K  10
#define NITER 20
#define RTOL_ 1e-5f
#define ATOL_ 1e-6f

// ---------------- device state (fully re-derived every launch) ----------------
__device__ __align__(4)  unsigned char g_valid[HW];
__device__ __align__(4)  unsigned char g_labels[HW];
__device__ float g_tok_sq[HW];
__device__ float g_r[HW];
__device__ __align__(16) float g_cent[K * C];
__device__ __align__(16) float g_sums[K * C];
__device__ float g_csq[K];
__device__ float g_counts[K];
__device__ unsigned g_done;

// ---------------- prep: valid[] and tok_sq[] ----------------
// tok_sq accumulated in f64 (error ~1e-13, order-independent), rounded to f32:
// the correctly-rounded value every f32 reference family approximates.
__global__ __launch_bounds__(256) void prep_kernel(const float* __restrict__ X,
                                                   const float* __restrict__ mask) {
    const int hw = blockIdx.x * 256 + threadIdx.x;
    const float mb = (mask[hw] > 0.0f) ? 1.0f : 0.0f;
    const float* xp = X + hw;
    int any = 0;
    double a0 = 0.0, a1 = 0.0, a2 = 0.0, a3 = 0.0;
    for (int c = 0; c < C; c += 4) {
        float v0 = xp[(size_t)(c + 0) * HW] * mb;
        float v1 = xp[(size_t)(c + 1) * HW] * mb;
        float v2 = xp[(size_t)(c + 2) * HW] * mb;
        float v3 = xp[(size_t)(c + 3) * HW] * mb;
        any |= (v0 != 0.0f) | (v1 != 0.0f) | (v2 != 0.0f) | (v3 != 0.0f);
        a0 = fma((double)v0, (double)v0, a0);
        a1 = fma((double)v1, (double)v1, a1);
        a2 = fma((double)v2, (double)v2, a2);
        a3 = fma((double)v3, (double)v3, a3);
    }
    g_valid[hw]  = any ? 1 : 0;
    g_tok_sq[hw] = (float)((a0 + a1) + (a2 + a3));
}

// f64-accurate sum of squares over a contiguous 2048-float row -> f32.
__device__ float csq_f64(const float* __restrict__ cp) {
    double a0 = 0.0, a1 = 0.0, a2 = 0.0, a3 = 0.0;
    for (int c = 0; c < C; c += 4) {
        double v0 = (double)cp[c + 0];
        double v1 = (double)cp[c + 1];
        double v2 = (double)cp[c + 2];
        double v3 = (double)cp[c + 3];
        a0 = fma(v0, v0, a0);
        a1 = fma(v1, v1, a1);
        a2 = fma(v2, v2, a2);
        a3 = fma(v3, v3, a3);
    }
    return (float)((a0 + a1) + (a2 + a3));
}

// ---------------- threefry2x32 (JAX partitionable), key=(0,42) ----------------
// counter=(hi=0, lo=i); 32-bit draw = out0 ^ out1 (CONFIRMED by R6 error drop).
__device__ __forceinline__ uint32_t rotl32(uint32_t v, int d) {
    return (v << d) | (v >> (32 - d));
}

__global__ void rng_kernel() {
    int i = blockIdx.x * blockDim.x + threadIdx.x;
    if (i >= HW) return;
    const uint32_t k0 = 0u, k1 = 42u;
    uint32_t ks[3] = {k0, k1, k0 ^ k1 ^ 0x1BD11BDAu};
    uint32_t x0 = 0u + ks[0];
    uint32_t x1 = (uint32_t)i + ks[1];
    const int rot[2][4] = {{13, 15, 26, 6}, {17, 29, 16, 24}};
#pragma unroll
    for (int g = 0; g < 5; ++g) {
#pragma unroll
        for (int j = 0; j < 4; ++j) {
            x0 += x1;
            x1 = rotl32(x1, rot[g & 1][j]);
            x1 ^= x0;
        }
        x0 += ks[(g + 1) % 3];
        x1 += ks[(g + 2) % 3] + (uint32_t)(g + 1);
    }
    uint32_t bits = x0 ^ x1;  // fold both output words
    float u = __uint_as_float((bits >> 9) | 0x3f800000u) - 1.0f;
    g_r[i] = g_valid[i] ? u : 2.0f;
}

// ---------------- init selection + gather + zero + csq ----------------
__global__ __launch_bounds__(1024) void select_kernel(const float* __restrict__ X,
                                                      const float* __restrict__ mask) {
    __shared__ unsigned long long red[1024];
    __shared__ int sh_idx[K];
    const int tid = threadIdx.x;
    for (int round = 0; round < K; ++round) {
        unsigned long long best = ~0ull;
        for (int i = tid; i < HW; i += 1024) {
            float v = g_r[i];
            unsigned long long key =
                ((unsigned long long)__float_as_uint(v) << 32) | (unsigned)i;
            if (key < best) best = key;
        }
        red[tid] = best;
        __syncthreads();
        for (int off = 512; off > 0; off >>= 1) {
            if (tid < off && red[tid + off] < red[tid]) red[tid] = red[tid + off];
            __syncthreads();
        }
        if (tid == 0) {
            int idx = (int)(red[0] & 0xffffffffu);
            sh_idx[round] = idx;
            g_r[idx] = 3.0f;  // exclude from later rounds
        }
        __syncthreads();
    }
    for (int e = tid; e < K * C; e += 1024) {
        int k = e >> 11, c = e & (C - 1);
        int id = sh_idx[k];
        float mb = (mask[id] > 0.0f) ? 1.0f : 0.0f;
        g_cent[e] = X[(size_t)c * HW + id] * mb;
    }
    if (tid < K) g_counts[tid] = 0.0f;
    if (tid == 0) g_done = 0u;
    __syncthreads();
    if (tid < K) g_csq[tid] = csq_f64(g_cent + tid * C);
}

// ---------------- label pass ----------------
// dot[k] accumulated in f64 (correctly-rounded input), rounded to f32; the
// reference's f32 cancellation (tsq - 2*dot) + csq applied on the f32 values.
__global__ __launch_bounds__(256) void label_kernel(const float* __restrict__ X) {
#pragma clang fp contract(off)
    __shared__ __align__(16) float scent[K * C];  // 80 KB
    __shared__ float scsq[K];
    __shared__ int   shist[K];
    const int t = threadIdx.x;
    for (int j = t; j < (K * C) / 4; j += 256)
        ((float4*)scent)[j] = ((const float4*)g_cent)[j];
    if (t < K) { scsq[t] = g_csq[t]; shist[t] = 0; }
    __syncthreads();

    const int hw = blockIdx.x * 256 + t;
    double acc[K];
#pragma unroll
    for (int k = 0; k < K; ++k) acc[k] = 0.0;
    const float* xp = X + hw;
    for (int c = 0; c < C; c += 4) {
        double x0 = (double)xp[(size_t)(c + 0) * HW];
        double x1 = (double)xp[(size_t)(c + 1) * HW];
        double x2 = (double)xp[(size_t)(c + 2) * HW];
        double x3 = (double)xp[(size_t)(c + 3) * HW];
#pragma unroll
        for (int k = 0; k < K; ++k) {
            const float4 cv = *(const float4*)&scent[k * C + c];
            double a = acc[k];
            a = fma(x0, (double)cv.x, a);
            a = fma(x1, (double)cv.y, a);
            a = fma(x2, (double)cv.z, a);
            a = fma(x3, (double)cv.w, a);
            acc[k] = a;
        }
    }
    const float tsq = g_tok_sq[hw];
    float best = INFINITY;
    int bl = 0;
#pragma unroll
    for (int k = 0; k < K; ++k) {
        float dotf = (float)acc[k];          // correctly-rounded f32 dot
        float twod = 2.0f * dotf;            // exact (power of 2)
        float d2 = (tsq - twod) + scsq[k];   // reference's f32 grid
        if (d2 < best) { best = d2; bl = k; }
    }
    const int valid = g_valid[hw];
    g_labels[hw] = valid ? (unsigned char)bl : (unsigned char)255;
    if (valid) atomicAdd(&shist[bl], 1);
    __syncthreads();
    if (t < K) atomicAdd(&g_counts[t], (float)shist[t]);
}

// ---------------- sum pass ----------------
// One thread per (k, c): serial f32 add-chain over i ascending (BLAS family).
__global__ __launch_bounds__(256) void sum_kernel(const float* __restrict__ X) {
#pragma clang fp contract(off)
    __shared__ unsigned int slab[HW / 4];  // 25600 labels as packed bytes
    const int tid = threadIdx.x;
    for (int j = tid; j < HW / 4; j += 256)
        slab[j] = ((const unsigned int*)g_labels)[j];
    __syncthreads();
    const int e = blockIdx.x * 256 + tid;  // 0..20479
    const int c = e / K;
    const unsigned k = (unsigned)(e - c * K);
    const float4* xr = (const float4*)(X + (size_t)c * HW);
    float acc = 0.0f;
    for (int i4 = 0; i4 < HW / 4; ++i4) {
        const float4 x = xr[i4];
        const unsigned lw = slab[i4];
        acc = acc + ((((lw      ) & 0xffu) == k) ? x.x : 0.0f);
        acc = acc + ((((lw >>  8) & 0xffu) == k) ? x.y : 0.0f);
        acc = acc + ((((lw >> 16) & 0xffu) == k) ? x.z : 0.0f);
        acc = acc + ((( lw >> 24         ) == k) ? x.w : 0.0f);
    }
    g_sums[k * C + c] = acc;
}

// ---------------- update / convergence / csq ----------------
__global__ __launch_bounds__(1024) void update_kernel(int last, float* __restrict__ out) {
#pragma clang fp contract(off)
    __shared__ float sh_counts[K];
    __shared__ int s_conv;
    __shared__ unsigned s_done;
    const int tid = threadIdx.x;
    if (tid == 0) { s_conv = 1; s_done = g_done; }
    if (tid < K) sh_counts[tid] = g_counts[tid];
    __syncthreads();
    const bool dn = (s_done != 0);
    float newv[20], oldv[20];
    int convLocal = 1;
#pragma unroll
    for (int j = 0; j < 20; ++j) {
        int e = tid + j * 1024;
        int k = e >> 11;
        float cnt = sh_counts[k];
        float cv = g_cent[e];
        float nv = (cnt > 0.0f) ? (g_sums[e] / fmaxf(cnt, 1.0f)) : cv;
        newv[j] = nv;
        oldv[j] = cv;
        float tol = RTOL_ * fabsf(nv);   // rounded mul
        tol = ATOL_ + tol;               // rounded add
        float diff = fabsf(cv - nv);
        if (!(diff <= tol)) convLocal = 0;
    }
    if (!convLocal) atomicAnd(&s_conv, 0);
    __syncthreads();
    const bool conv = (s_conv != 0);
    const bool upd = (!dn && !conv);
#pragma unroll
    for (int j = 0; j < 20; ++j) {
        int e = tid + j * 1024;
        float fv = upd ? newv[j] : oldv[j];
        if (upd) g_cent[e] = fv;
        if (last) out[e] = fv;
    }
    if (tid == 0 && conv && !dn) g_done = 1u;
    if (tid < K) g_counts[tid] = 0.0f;
    __syncthreads();
    if (tid < K) g_csq[tid] = csq_f64(g_cent + tid * C);
}

extern "C" void kernel_launch(void* const* d_in, const int* in_sizes, int n_in,
                              void* d_out, int out_size, void* d_ws, size_t ws_size,
                              hipStream_t stream) {
    const float* X = (const float*)d_in[0];     // [2048, 160*160] flat
    const float* mask = (const float*)d_in[1];  // [160*160]
    float* out = (float*)d_out;                 // [10, 2048]
    (void)in_sizes; (void)n_in; (void)out_size; (void)d_ws; (void)ws_size;

    prep_kernel<<<HW / 256, 256, 0, stream>>>(X, mask);
    rng_kernel<<<(HW + 255) / 256, 256, 0, stream>>>();
    select_kernel<<<1, 1024, 0, stream>>>(X, mask);
    for (int it = 0; it < NITER; ++it) {
        label_kernel<<<HW / 256, 256, 0, stream>>>(X);
        sum_kernel<<<(K * C) / 256, 256, 0, stream>>>(X);
        update_kernel<<<1, 1024, 0, stream>>>(it == NITER - 1 ? 1 : 0, out);
    }
}

// Round 11
// 5572.815 us; speedup vs baseline: 2.4885x; 2.4885x over previous
//
#include <hip/hip_runtime.h>
#include <stdint.h>

#define HW 25600
#define C  2048
#define K  10
#define NITER 20
#define RTOL_ 1e-5f
#define ATOL_ 1e-6f

// ---------------- device state (fully re-derived every launch) ----------------
__device__ __align__(4) unsigned char g_valid[HW];
__device__ __align__(4) unsigned char g_labels[HW];
__device__ float g_tok_sq[HW];
__device__ float g_r[HW];
__device__ __align__(16) float g_cent[K * C];
__device__ __align__(16) float g_sums[K * C];
__device__ float g_csq[K];
__device__ int   g_counts[K];
__device__ unsigned g_done;
// scratch for parallel f64 partial reductions (f64 reassociation is safe:
// noise ~1e-16 rel, absorbed by the final f64->f32 rounding — R8/R9 evidence)
__device__ double g_part[4 * K * HW];      // label partial dots  (8.2 MB)
__device__ double g_psq[8 * HW];           // prep partial sumsq
__device__ unsigned char g_pany[8 * HW];

// ---------------- prep A: per-chunk f64 partial sumsq + any ----------------
// 800 blocks = 100 hw-blocks x 8 c-chunks of 256 channels.
__global__ __launch_bounds__(256) void prepA_kernel(const float* __restrict__ X,
                                                    const float* __restrict__ mask) {
    const int chunk = blockIdx.x & 7;
    const int hw = (blockIdx.x >> 3) * 256 + threadIdx.x;
    const float mb = (mask[hw] > 0.0f) ? 1.0f : 0.0f;
    const float* xp = X + hw + (size_t)(chunk * 256) * HW;
    double a = 0.0;
    int any = 0;
    for (int cc = 0; cc < 256; ++cc) {
        float v = xp[(size_t)cc * HW] * mb;   // exact f32 product (mb in {0,1})
        any |= (v != 0.0f);
        a = fma((double)v, (double)v, a);
    }
    g_psq[chunk * HW + hw] = a;
    g_pany[chunk * HW + hw] = (unsigned char)any;
}

// ---------------- prep B: combine partials -> tok_sq (f32), valid ----------------
__global__ __launch_bounds__(256) void prepB_kernel() {
    const int hw = blockIdx.x * 256 + threadIdx.x;
    double s0 = (g_psq[0 * HW + hw] + g_psq[1 * HW + hw]) +
                (g_psq[2 * HW + hw] + g_psq[3 * HW + hw]);
    double s1 = (g_psq[4 * HW + hw] + g_psq[5 * HW + hw]) +
                (g_psq[6 * HW + hw] + g_psq[7 * HW + hw]);
    g_tok_sq[hw] = (float)(s0 + s1);
    int any = 0;
#pragma unroll
    for (int j = 0; j < 8; ++j) any |= g_pany[j * HW + hw];
    g_valid[hw] = any ? 1 : 0;
}

// ---------------- threefry2x32 (JAX partitionable), key=(0,42) ----------------
// counter=(hi=0, lo=i); 32-bit draw = out0 ^ out1 (CONFIRMED R6/R10).
__device__ __forceinline__ uint32_t rotl32(uint32_t v, int d) {
    return (v << d) | (v >> (32 - d));
}

__global__ void rng_kernel() {
    int i = blockIdx.x * blockDim.x + threadIdx.x;
    if (i >= HW) return;
    const uint32_t k0 = 0u, k1 = 42u;
    uint32_t ks[3] = {k0, k1, k0 ^ k1 ^ 0x1BD11BDAu};
    uint32_t x0 = 0u + ks[0];
    uint32_t x1 = (uint32_t)i + ks[1];
    const int rot[2][4] = {{13, 15, 26, 6}, {17, 29, 16, 24}};
#pragma unroll
    for (int g = 0; g < 5; ++g) {
#pragma unroll
        for (int j = 0; j < 4; ++j) {
            x0 += x1;
            x1 = rotl32(x1, rot[g & 1][j]);
            x1 ^= x0;
        }
        x0 += ks[(g + 1) % 3];
        x1 += ks[(g + 2) % 3] + (uint32_t)(g + 1);
    }
    uint32_t bits = x0 ^ x1;
    float u = __uint_as_float((bits >> 9) | 0x3f800000u) - 1.0f;
    g_r[i] = g_valid[i] ? u : 2.0f;
}

// f64-accurate sum of squares over a contiguous 2048-float row -> f32.
__device__ float csq_f64(const float* __restrict__ cp) {
    double a0 = 0.0, a1 = 0.0, a2 = 0.0, a3 = 0.0;
    for (int c = 0; c < C; c += 4) {
        double v0 = (double)cp[c + 0];
        double v1 = (double)cp[c + 1];
        double v2 = (double)cp[c + 2];
        double v3 = (double)cp[c + 3];
        a0 = fma(v0, v0, a0);
        a1 = fma(v1, v1, a1);
        a2 = fma(v2, v2, a2);
        a3 = fma(v3, v3, a3);
    }
    return (float)((a0 + a1) + (a2 + a3));
}

// ---------------- init selection + gather + zero + csq ----------------
__global__ __launch_bounds__(1024) void select_kernel(const float* __restrict__ X,
                                                      const float* __restrict__ mask) {
    __shared__ unsigned long long red[1024];
    __shared__ int sh_idx[K];
    const int tid = threadIdx.x;
    for (int round = 0; round < K; ++round) {
        unsigned long long best = ~0ull;
        for (int i = tid; i < HW; i += 1024) {
            float v = g_r[i];
            unsigned long long key =
                ((unsigned long long)__float_as_uint(v) << 32) | (unsigned)i;
            if (key < best) best = key;
        }
        red[tid] = best;
        __syncthreads();
        for (int off = 512; off > 0; off >>= 1) {
            if (tid < off && red[tid + off] < red[tid]) red[tid] = red[tid + off];
            __syncthreads();
        }
        if (tid == 0) {
            int idx = (int)(red[0] & 0xffffffffu);
            sh_idx[round] = idx;
            g_r[idx] = 3.0f;
        }
        __syncthreads();
    }
    for (int e = tid; e < K * C; e += 1024) {
        int k = e >> 11, c = e & (C - 1);
        int id = sh_idx[k];
        float mb = (mask[id] > 0.0f) ? 1.0f : 0.0f;
        g_cent[e] = X[(size_t)c * HW + id] * mb;
    }
    if (tid < K) g_counts[tid] = 0;
    if (tid == 0) g_done = 0u;
    __syncthreads();
    if (tid < K) g_csq[tid] = csq_f64(g_cent + tid * C);
}

// ---------------- label pass 1: f64 partial dots over c-chunks ----------------
// 400 blocks = 100 hw-blocks x 4 c-chunks of 512. LDS 20 KB.
__global__ __launch_bounds__(256) void label1_kernel(const float* __restrict__ X) {
    if (g_done) return;
    const int chunk = blockIdx.x & 3;
    const int hwblk = blockIdx.x >> 2;
    const int c0 = chunk * 512;
    __shared__ __align__(16) float scent[K][512];
    const int t = threadIdx.x;
    for (int j = t; j < K * 128; j += 256) {
        int k = j >> 7, q = j & 127;
        ((float4*)scent[k])[q] = *(const float4*)&g_cent[k * C + c0 + q * 4];
    }
    __syncthreads();
    const int hw = hwblk * 256 + t;
    double acc[K];
#pragma unroll
    for (int k = 0; k < K; ++k) acc[k] = 0.0;
    const float* xp = X + hw + (size_t)c0 * HW;
    for (int cc = 0; cc < 512; cc += 4) {
        double x0 = (double)xp[(size_t)(cc + 0) * HW];
        double x1 = (double)xp[(size_t)(cc + 1) * HW];
        double x2 = (double)xp[(size_t)(cc + 2) * HW];
        double x3 = (double)xp[(size_t)(cc + 3) * HW];
#pragma unroll
        for (int k = 0; k < K; ++k) {
            const float4 cv = *(const float4*)&scent[k][cc];
            double a = acc[k];
            a = fma(x0, (double)cv.x, a);
            a = fma(x1, (double)cv.y, a);
            a = fma(x2, (double)cv.z, a);
            a = fma(x3, (double)cv.w, a);
            acc[k] = a;
        }
    }
#pragma unroll
    for (int k = 0; k < K; ++k) g_part[(chunk * K + k) * HW + hw] = acc[k];
}

// ---------------- label pass 2: combine, f32 d2 grid, argmin, hist ----------------
__global__ __launch_bounds__(256) void label2_kernel() {
#pragma clang fp contract(off)
    if (g_done) return;
    __shared__ int shist[K];
    const int t = threadIdx.x;
    if (t < K) shist[t] = 0;
    __syncthreads();
    const int hw = blockIdx.x * 256 + t;
    const float tsq = g_tok_sq[hw];
    float best = INFINITY;
    int bl = 0;
#pragma unroll
    for (int k = 0; k < K; ++k) {
        double d = (g_part[(0 * K + k) * HW + hw] + g_part[(1 * K + k) * HW + hw]) +
                   (g_part[(2 * K + k) * HW + hw] + g_part[(3 * K + k) * HW + hw]);
        float dotf = (float)d;               // correctly-rounded f32 dot
        float twod = 2.0f * dotf;            // exact
        float d2 = (tsq - twod) + g_csq[k];  // reference's f32 grid
        if (d2 < best) { best = d2; bl = k; }
    }
    const int valid = g_valid[hw];
    g_labels[hw] = valid ? (unsigned char)bl : (unsigned char)255;
    if (valid) atomicAdd(&shist[bl], 1);
    __syncthreads();
    if (t < K) atomicAdd(&g_counts[t], shist[t]);
}

// ---------------- sum pass: wave per channel, f64 acc, shuffle reduce ----------------
// 512 blocks x 4 waves; X read exactly once; no atomics.
__global__ __launch_bounds__(256) void sum_kernel(const float* __restrict__ X) {
    if (g_done) return;
    __shared__ unsigned slab[HW / 4];
    const int t = threadIdx.x;
    for (int j = t; j < HW / 4; j += 256) slab[j] = ((const unsigned*)g_labels)[j];
    __syncthreads();
    const int wv = t >> 6, lane = t & 63;
    const int row = blockIdx.x * 4 + wv;
    const float* xr = X + (size_t)row * HW;
    const unsigned char* lb = (const unsigned char*)slab;
    double acc[K];
#pragma unroll
    for (int k = 0; k < K; ++k) acc[k] = 0.0;
    for (int i = lane; i < HW; i += 64) {
        double x = (double)xr[i];
        int l = lb[i];
#pragma unroll
        for (int k = 0; k < K; ++k) acc[k] += (l == k) ? x : 0.0;
    }
#pragma unroll
    for (int k = 0; k < K; ++k) {
#pragma unroll
        for (int off = 32; off > 0; off >>= 1) acc[k] += __shfl_down(acc[k], off, 64);
    }
    if (lane == 0) {
#pragma unroll
        for (int k = 0; k < K; ++k) g_sums[k * C + row] = (float)acc[k];
    }
}

// ---------------- update / convergence / csq ----------------
__global__ __launch_bounds__(1024) void update_kernel(int last, float* __restrict__ out) {
#pragma clang fp contract(off)
    __shared__ float sh_counts[K];
    __shared__ int s_conv;
    __shared__ unsigned s_done;
    const int tid = threadIdx.x;
    if (tid == 0) { s_conv = 1; s_done = g_done; }
    if (tid < K) sh_counts[tid] = (float)g_counts[tid];
    __syncthreads();
    const bool dn = (s_done != 0);
    float newv[20], oldv[20];
    int convLocal = 1;
#pragma unroll
    for (int j = 0; j < 20; ++j) {
        int e = tid + j * 1024;
        int k = e >> 11;
        float cnt = sh_counts[k];
        float cv = g_cent[e];
        float nv = (cnt > 0.0f) ? (g_sums[e] / fmaxf(cnt, 1.0f)) : cv;
        newv[j] = nv;
        oldv[j] = cv;
        float tol = RTOL_ * fabsf(nv);   // rounded mul
        tol = ATOL_ + tol;               // rounded add
        float diff = fabsf(cv - nv);
        if (!(diff <= tol)) convLocal = 0;
    }
    if (!convLocal) atomicAnd(&s_conv, 0);
    __syncthreads();
    const bool conv = (s_conv != 0);
    const bool upd = (!dn && !conv);
#pragma unroll
    for (int j = 0; j < 20; ++j) {
        int e = tid + j * 1024;
        float fv = upd ? newv[j] : oldv[j];
        if (upd) g_cent[e] = fv;
        if (last) out[e] = fv;
    }
    if (tid == 0 && conv && !dn) g_done = 1u;
    if (tid < K) g_counts[tid] = 0;
    __syncthreads();
    // csq: wave per cluster, f64 accumulate -> shuffle reduce -> f32
    const int wv = tid >> 6, lane = tid & 63;
    if (wv < K) {
        double a = 0.0;
        for (int c = lane; c < C; c += 64) {
            double v = (double)g_cent[wv * C + c];
            a = fma(v, v, a);
        }
#pragma unroll
        for (int off = 32; off > 0; off >>= 1) a += __shfl_down(a, off, 64);
        if (lane == 0) g_csq[wv] = (float)a;
    }
}

extern "C" void kernel_launch(void* const* d_in, const int* in_sizes, int n_in,
                              void* d_out, int out_size, void* d_ws, size_t ws_size,
                              hipStream_t stream) {
    const float* X = (const float*)d_in[0];     // [2048, 160*160] flat
    const float* mask = (const float*)d_in[1];  // [160*160]
    float* out = (float*)d_out;                 // [10, 2048]
    (void)in_sizes; (void)n_in; (void)out_size; (void)d_ws; (void)ws_size;

    prepA_kernel<<<800, 256, 0, stream>>>(X, mask);
    prepB_kernel<<<100, 256, 0, stream>>>();
    rng_kernel<<<100, 256, 0, stream>>>();
    select_kernel<<<1, 1024, 0, stream>>>(X, mask);
    for (int it = 0; it < NITER; ++it) {
        label1_kernel<<<400, 256, 0, stream>>>(X);
        label2_kernel<<<100, 256, 0, stream>>>();
        sum_kernel<<<512, 256, 0, stream>>>(X);
        update_kernel<<<1, 1024, 0, stream>>>(it == NITER - 1 ? 1 : 0, out);
    }
}

// Round 12
// 3152.420 us; speedup vs baseline: 4.3992x; 1.7678x over previous
//
#include <hip/hip_runtime.h>
#include <stdint.h>

#define HW 25600
#define C  2048
#define K  10
#define NITER 20
#define RTOL_ 1e-5f
#define ATOL_ 1e-6f

// ---------------- device state (fully re-derived every launch) ----------------
__device__ __align__(4) unsigned char g_valid[HW];
__device__ __align__(4) unsigned char g_labels[HW];
__device__ float g_tok_sq[HW];
__device__ float g_r[HW];
__device__ __align__(16) float g_cent[K * C];
__device__ __align__(16) float g_sums[K * C];
__device__ float g_csq[K];
__device__ int   g_counts[K];
__device__ unsigned g_done;
// scratch for parallel f64 partial reductions (f64 reassociation is safe:
// noise ~1e-16 rel, absorbed by the final f64->f32 rounding — R10/R11 evidence)
__device__ double g_part[8 * K * HW];      // label partial dots (16.4 MB)
__device__ double g_psq[8 * HW];           // prep partial sumsq
__device__ unsigned char g_pany[8 * HW];

// ---------------- prep A: per-chunk f64 partial sumsq + any ----------------
// 800 blocks = 100 hw-blocks x 8 c-chunks of 256 channels.
__global__ __launch_bounds__(256) void prepA_kernel(const float* __restrict__ X,
                                                    const float* __restrict__ mask) {
    const int chunk = blockIdx.x & 7;
    const int hw = (blockIdx.x >> 3) * 256 + threadIdx.x;
    const float mb = (mask[hw] > 0.0f) ? 1.0f : 0.0f;
    const float* xp = X + hw + (size_t)(chunk * 256) * HW;
    double a = 0.0;
    int any = 0;
    for (int cc = 0; cc < 256; ++cc) {
        float v = xp[(size_t)cc * HW] * mb;   // exact f32 product (mb in {0,1})
        any |= (v != 0.0f);
        a = fma((double)v, (double)v, a);
    }
    g_psq[chunk * HW + hw] = a;
    g_pany[chunk * HW + hw] = (unsigned char)any;
}

// ---------------- prep B: combine partials -> tok_sq (f32), valid ----------------
__global__ __launch_bounds__(256) void prepB_kernel() {
    const int hw = blockIdx.x * 256 + threadIdx.x;
    double s0 = (g_psq[0 * HW + hw] + g_psq[1 * HW + hw]) +
                (g_psq[2 * HW + hw] + g_psq[3 * HW + hw]);
    double s1 = (g_psq[4 * HW + hw] + g_psq[5 * HW + hw]) +
                (g_psq[6 * HW + hw] + g_psq[7 * HW + hw]);
    g_tok_sq[hw] = (float)(s0 + s1);
    int any = 0;
#pragma unroll
    for (int j = 0; j < 8; ++j) any |= g_pany[j * HW + hw];
    g_valid[hw] = any ? 1 : 0;
}

// ---------------- threefry2x32 (JAX partitionable), key=(0,42) ----------------
// counter=(hi=0, lo=i); 32-bit draw = out0 ^ out1 (CONFIRMED R6/R10/R11).
__device__ __forceinline__ uint32_t rotl32(uint32_t v, int d) {
    return (v << d) | (v >> (32 - d));
}

__global__ void rng_kernel() {
    int i = blockIdx.x * blockDim.x + threadIdx.x;
    if (i >= HW) return;
    const uint32_t k0 = 0u, k1 = 42u;
    uint32_t ks[3] = {k0, k1, k0 ^ k1 ^ 0x1BD11BDAu};
    uint32_t x0 = 0u + ks[0];
    uint32_t x1 = (uint32_t)i + ks[1];
    const int rot[2][4] = {{13, 15, 26, 6}, {17, 29, 16, 24}};
#pragma unroll
    for (int g = 0; g < 5; ++g) {
#pragma unroll
        for (int j = 0; j < 4; ++j) {
            x0 += x1;
            x1 = rotl32(x1, rot[g & 1][j]);
            x1 ^= x0;
        }
        x0 += ks[(g + 1) % 3];
        x1 += ks[(g + 2) % 3] + (uint32_t)(g + 1);
    }
    uint32_t bits = x0 ^ x1;
    float u = __uint_as_float((bits >> 9) | 0x3f800000u) - 1.0f;
    g_r[i] = g_valid[i] ? u : 2.0f;
}

// f64-accurate sum of squares over a contiguous 2048-float row -> f32.
__device__ float csq_f64(const float* __restrict__ cp) {
    double a0 = 0.0, a1 = 0.0, a2 = 0.0, a3 = 0.0;
    for (int c = 0; c < C; c += 4) {
        double v0 = (double)cp[c + 0];
        double v1 = (double)cp[c + 1];
        double v2 = (double)cp[c + 2];
        double v3 = (double)cp[c + 3];
        a0 = fma(v0, v0, a0);
        a1 = fma(v1, v1, a1);
        a2 = fma(v2, v2, a2);
        a3 = fma(v3, v3, a3);
    }
    return (float)((a0 + a1) + (a2 + a3));
}

// ---------------- init selection + gather + zero + csq ----------------
__global__ __launch_bounds__(1024) void select_kernel(const float* __restrict__ X,
                                                      const float* __restrict__ mask) {
    __shared__ unsigned long long red[1024];
    __shared__ int sh_idx[K];
    const int tid = threadIdx.x;
    for (int round = 0; round < K; ++round) {
        unsigned long long best = ~0ull;
        for (int i = tid; i < HW; i += 1024) {
            float v = g_r[i];
            unsigned long long key =
                ((unsigned long long)__float_as_uint(v) << 32) | (unsigned)i;
            if (key < best) best = key;
        }
        red[tid] = best;
        __syncthreads();
        for (int off = 512; off > 0; off >>= 1) {
            if (tid < off && red[tid + off] < red[tid]) red[tid] = red[tid + off];
            __syncthreads();
        }
        if (tid == 0) {
            int idx = (int)(red[0] & 0xffffffffu);
            sh_idx[round] = idx;
            g_r[idx] = 3.0f;
        }
        __syncthreads();
    }
    for (int e = tid; e < K * C; e += 1024) {
        int k = e >> 11, c = e & (C - 1);
        int id = sh_idx[k];
        float mb = (mask[id] > 0.0f) ? 1.0f : 0.0f;
        g_cent[e] = X[(size_t)c * HW + id] * mb;
    }
    if (tid < K) g_counts[tid] = 0;
    if (tid == 0) g_done = 0u;
    __syncthreads();
    if (tid < K) g_csq[tid] = csq_f64(g_cent + tid * C);
}

// ---------------- label pass 1: f64 partial dots over c-chunks ----------------
// 800 blocks = 100 hw-blocks x 8 c-chunks of 256 channels. LDS 20 KB (f64 cent).
__global__ __launch_bounds__(256) void label1_kernel(const float* __restrict__ X) {
    if (g_done) return;
    const int chunk = blockIdx.x & 7;
    const int hwblk = blockIdx.x >> 3;
    const int c0 = chunk * 256;
    __shared__ __align__(16) double scent[K][256];  // 20 KB
    const int t = threadIdx.x;
    for (int j = t; j < K * 256; j += 256) {
        int k = j >> 8, q = j & 255;
        scent[k][q] = (double)g_cent[k * C + c0 + q];
    }
    __syncthreads();
    const int hw = hwblk * 256 + t;
    double acc[K];
#pragma unroll
    for (int k = 0; k < K; ++k) acc[k] = 0.0;
    const float* xp = X + hw + (size_t)c0 * HW;
    for (int cc = 0; cc < 256; cc += 2) {
        double x0 = (double)xp[(size_t)(cc + 0) * HW];
        double x1 = (double)xp[(size_t)(cc + 1) * HW];
#pragma unroll
        for (int k = 0; k < K; ++k) {
            const double2 cv = *(const double2*)&scent[k][cc];
            double a = acc[k];
            a = fma(x0, cv.x, a);
            a = fma(x1, cv.y, a);
            acc[k] = a;
        }
    }
#pragma unroll
    for (int k = 0; k < K; ++k) g_part[(chunk * K + k) * HW + hw] = acc[k];
}

// ---------------- label pass 2: combine, f32 d2 grid, argmin, hist ----------------
__global__ __launch_bounds__(256) void label2_kernel() {
#pragma clang fp contract(off)
    if (g_done) return;
    __shared__ int shist[K];
    const int t = threadIdx.x;
    if (t < K) shist[t] = 0;
    __syncthreads();
    const int hw = blockIdx.x * 256 + t;
    const float tsq = g_tok_sq[hw];
    float best = INFINITY;
    int bl = 0;
#pragma unroll
    for (int k = 0; k < K; ++k) {
        double p0 = g_part[(0 * K + k) * HW + hw], p1 = g_part[(1 * K + k) * HW + hw];
        double p2 = g_part[(2 * K + k) * HW + hw], p3 = g_part[(3 * K + k) * HW + hw];
        double p4 = g_part[(4 * K + k) * HW + hw], p5 = g_part[(5 * K + k) * HW + hw];
        double p6 = g_part[(6 * K + k) * HW + hw], p7 = g_part[(7 * K + k) * HW + hw];
        double d = ((p0 + p1) + (p2 + p3)) + ((p4 + p5) + (p6 + p7));
        float dotf = (float)d;               // correctly-rounded f32 dot
        float twod = 2.0f * dotf;            // exact
        float d2 = (tsq - twod) + g_csq[k];  // reference's f32 grid
        if (d2 < best) { best = d2; bl = k; }
    }
    const int valid = g_valid[hw];
    g_labels[hw] = valid ? (unsigned char)bl : (unsigned char)255;
    if (valid) atomicAdd(&shist[bl], 1);
    __syncthreads();
    if (t < K) atomicAdd(&g_counts[t], shist[t]);
}

// ---------------- sum pass: block per channel, 4 waves x quarter-row ----------------
// float4 x-loads + packed u32 labels; f64 compare-select acc; shuffle+LDS combine.
__global__ __launch_bounds__(256) void sum_kernel(const float* __restrict__ X) {
    if (g_done) return;
    const int c = blockIdx.x;
    const int wv = threadIdx.x >> 6, lane = threadIdx.x & 63;
    const int base = wv * (HW / 4);  // quarter-row start (6400 elements)
    const float4* xr = (const float4*)(X + (size_t)c * HW + base);
    const unsigned* lw = (const unsigned*)(g_labels + base);
    double acc[K];
#pragma unroll
    for (int k = 0; k < K; ++k) acc[k] = 0.0;
    for (int t = 0; t < 25; ++t) {
        const int idx = t * 64 + lane;       // float4 index within quarter
        const float4 x = xr[idx];
        const unsigned w = lw[idx];
        const int l0 = (int)(w & 255u), l1 = (int)((w >> 8) & 255u);
        const int l2 = (int)((w >> 16) & 255u), l3 = (int)(w >> 24);
        const double x0 = (double)x.x, x1 = (double)x.y;
        const double x2 = (double)x.z, x3 = (double)x.w;
#pragma unroll
        for (int k = 0; k < K; ++k) {
            double a = acc[k];
            a += (l0 == k) ? x0 : 0.0;
            a += (l1 == k) ? x1 : 0.0;
            a += (l2 == k) ? x2 : 0.0;
            a += (l3 == k) ? x3 : 0.0;
            acc[k] = a;
        }
    }
#pragma unroll
    for (int k = 0; k < K; ++k) {
#pragma unroll
        for (int off = 32; off > 0; off >>= 1) acc[k] += __shfl_down(acc[k], off, 64);
    }
    __shared__ double comb[4][K];
    if (lane == 0) {
#pragma unroll
        for (int k = 0; k < K; ++k) comb[wv][k] = acc[k];
    }
    __syncthreads();
    if (threadIdx.x < K) {
        const int k = threadIdx.x;
        double s = (comb[0][k] + comb[1][k]) + (comb[2][k] + comb[3][k]);
        g_sums[k * C + c] = (float)s;
    }
}

// ---------------- update / convergence / csq ----------------
__global__ __launch_bounds__(1024) void update_kernel(int last, float* __restrict__ out) {
#pragma clang fp contract(off)
    __shared__ float sh_counts[K];
    __shared__ int s_conv;
    __shared__ unsigned s_done;
    const int tid = threadIdx.x;
    if (tid == 0) { s_conv = 1; s_done = g_done; }
    if (tid < K) sh_counts[tid] = (float)g_counts[tid];
    __syncthreads();
    const bool dn = (s_done != 0);
    float newv[20], oldv[20];
    int convLocal = 1;
#pragma unroll
    for (int j = 0; j < 20; ++j) {
        int e = tid + j * 1024;
        int k = e >> 11;
        float cnt = sh_counts[k];
        float cv = g_cent[e];
        float nv = (cnt > 0.0f) ? (g_sums[e] / fmaxf(cnt, 1.0f)) : cv;
        newv[j] = nv;
        oldv[j] = cv;
        float tol = RTOL_ * fabsf(nv);   // rounded mul
        tol = ATOL_ + tol;               // rounded add
        float diff = fabsf(cv - nv);
        if (!(diff <= tol)) convLocal = 0;
    }
    if (!convLocal) atomicAnd(&s_conv, 0);
    __syncthreads();
    const bool conv = (s_conv != 0);
    const bool upd = (!dn && !conv);
#pragma unroll
    for (int j = 0; j < 20; ++j) {
        int e = tid + j * 1024;
        float fv = upd ? newv[j] : oldv[j];
        if (upd) g_cent[e] = fv;
        if (last) out[e] = fv;
    }
    if (tid == 0 && conv && !dn) g_done = 1u;
    if (tid < K) g_counts[tid] = 0;
    __syncthreads();
    // csq: wave per cluster, f64 accumulate -> shuffle reduce -> f32
    const int wv = tid >> 6, lane = tid & 63;
    if (wv < K) {
        double a = 0.0;
        for (int c = lane; c < C; c += 64) {
            double v = (double)g_cent[wv * C + c];
            a = fma(v, v, a);
        }
#pragma unroll
        for (int off = 32; off > 0; off >>= 1) a += __shfl_down(a, off, 64);
        if (lane == 0) g_csq[wv] = (float)a;
    }
}

extern "C" void kernel_launch(void* const* d_in, const int* in_sizes, int n_in,
                              void* d_out, int out_size, void* d_ws, size_t ws_size,
                              hipStream_t stream) {
    const float* X = (const float*)d_in[0];     // [2048, 160*160] flat
    const float* mask = (const float*)d_in[1];  // [160*160]
    float* out = (float*)d_out;                 // [10, 2048]
    (void)in_sizes; (void)n_in; (void)out_size; (void)d_ws; (void)ws_size;

    prepA_kernel<<<800, 256, 0, stream>>>(X, mask);
    prepB_kernel<<<100, 256, 0, stream>>>();
    rng_kernel<<<100, 256, 0, stream>>>();
    select_kernel<<<1, 1024, 0, stream>>>(X, mask);
    for (int it = 0; it < NITER; ++it) {
        label1_kernel<<<800, 256, 0, stream>>>(X);
        label2_kernel<<<100, 256, 0, stream>>>();
        sum_kernel<<<C, 256, 0, stream>>>(X);
        update_kernel<<<1, 1024, 0, stream>>>(it == NITER - 1 ? 1 : 0, out);
    }
}